// Round 2
// baseline (99.434 us; speedup 1.0000x reference)
//
#include <hip/hip_runtime.h>
#include <math.h>

#define N_ROWS 16384
#define N_COLS 1000
#define WAVES_PER_BLOCK 16                     // 1024 threads
#define MAIN_BLOCKS (N_ROWS / WAVES_PER_BLOCK) // 1024

// ---------------------------------------------------------------------------
// Kernel 1: bincount of labels (single block, batched int4 loads, LDS
// atomics) + zero the output accumulator. ~3 µs.
// ---------------------------------------------------------------------------
__global__ __launch_bounds__(1024) void bincount_kernel(
    const int* __restrict__ label, int* __restrict__ counts,
    float* __restrict__ out) {
  __shared__ int cnt[N_COLS];
  for (int i = threadIdx.x; i < N_COLS; i += 1024) cnt[i] = 0;
  if (threadIdx.x == 0) out[0] = 0.0f;   // rowloss atomics accumulate here
  __syncthreads();

  // 16384 labels = 1024 threads x 4 int4 loads, coalesced, all independent.
  const int4* __restrict__ l4 = reinterpret_cast<const int4*>(label);
  int4 a = l4[threadIdx.x];
  int4 b = l4[threadIdx.x + 1024];
  int4 c = l4[threadIdx.x + 2048];
  int4 d = l4[threadIdx.x + 3072];
  atomicAdd(&cnt[a.x], 1); atomicAdd(&cnt[a.y], 1);
  atomicAdd(&cnt[a.z], 1); atomicAdd(&cnt[a.w], 1);
  atomicAdd(&cnt[b.x], 1); atomicAdd(&cnt[b.y], 1);
  atomicAdd(&cnt[b.z], 1); atomicAdd(&cnt[b.w], 1);
  atomicAdd(&cnt[c.x], 1); atomicAdd(&cnt[c.y], 1);
  atomicAdd(&cnt[c.z], 1); atomicAdd(&cnt[c.w], 1);
  atomicAdd(&cnt[d.x], 1); atomicAdd(&cnt[d.y], 1);
  atomicAdd(&cnt[d.z], 1); atomicAdd(&cnt[d.w], 1);
  __syncthreads();
  for (int i = threadIdx.x; i < N_COLS; i += 1024) counts[i] = cnt[i];
}

// ---------------------------------------------------------------------------
// Kernel 2: one wave per row; 16 waves per block. Row staged in 16 regs/lane
// via coalesced float4 loads. Wave-uniform scalar loads (label, counts,
// picked logit) issued FIRST so their latency hides under the vector loads.
// Block partial -> one fp32 atomicAdd to d_out (pre-zeroed by kernel 1).
// ---------------------------------------------------------------------------
__global__ __launch_bounds__(1024) void rowloss_kernel(
    const float* __restrict__ feature, const int* __restrict__ label,
    const int* __restrict__ counts, float* __restrict__ out) {
  const int wave = threadIdx.x >> 6;
  const int lane = threadIdx.x & 63;
  const int row  = blockIdx.x * WAVES_PER_BLOCK + wave;
  const float* rowp = feature + (size_t)row * N_COLS;

  // Early wave-uniform loads (broadcast); latency overlaps the float4 stream.
  const int   lab = label[row];
  const float ni  = (float)counts[lab];
  const float xl  = rowp[lab];

  // Coalesced register staging: step k covers elements [k*256, (k+1)*256);
  // lane l takes the float4 at element k*256 + l*4 (1024 B/wave/step).
  float4 v[4];
#pragma unroll
  for (int k = 0; k < 4; ++k) {
    const int e = k * 256 + lane * 4;
    if (e < N_COLS) {
      v[k] = *reinterpret_cast<const float4*>(rowp + e);
    } else {
      v[k] = make_float4(-INFINITY, -INFINITY, -INFINITY, -INFINITY);
    }
  }

  // Row max (butterfly over 64 lanes).
  float m = fmaxf(fmaxf(v[0].x, v[0].y), fmaxf(v[0].z, v[0].w));
#pragma unroll
  for (int k = 1; k < 4; ++k)
    m = fmaxf(m, fmaxf(fmaxf(v[k].x, v[k].y), fmaxf(v[k].z, v[k].w)));
#pragma unroll
  for (int off = 32; off > 0; off >>= 1) m = fmaxf(m, __shfl_xor(m, off));

  // sum(exp(x-m)) via exp2 (v_exp_f32); -inf pads contribute 0.
  const float LOG2E = 1.4426950408889634f;
  const float mL = m * LOG2E;
  float s = 0.0f;
#pragma unroll
  for (int k = 0; k < 4; ++k) {
    s += exp2f(fmaf(v[k].x, LOG2E, -mL));
    s += exp2f(fmaf(v[k].y, LOG2E, -mL));
    s += exp2f(fmaf(v[k].z, LOG2E, -mL));
    s += exp2f(fmaf(v[k].w, LOG2E, -mL));
  }
#pragma unroll
  for (int off = 32; off > 0; off >>= 1) s += __shfl_xor(s, off);

  // Epilogue on all lanes (wave-uniform values, no divergence).
  const float logp  = xl - m - logf(s);
  const float p     = expf(logp);
  const float beta  = (1.0f - p) * (1.0f - p);
  const float r     = ni * (1.0f / (float)N_ROWS);
  const float alpha = expf(r - 1.0f) / r;
  const float val   = alpha * beta * logp;

  __shared__ float wsum[WAVES_PER_BLOCK];
  if (lane == 0) wsum[wave] = val;
  __syncthreads();

  if (threadIdx.x < WAVES_PER_BLOCK) {
    float t = wsum[threadIdx.x];
#pragma unroll
    for (int off = WAVES_PER_BLOCK / 2; off > 0; off >>= 1)
      t += __shfl_xor(t, off);
    if (threadIdx.x == 0)
      atomicAdd(out, t * (-1.0f / (float)N_ROWS));
  }
}

// ---------------------------------------------------------------------------
extern "C" void kernel_launch(void* const* d_in, const int* in_sizes, int n_in,
                              void* d_out, int out_size, void* d_ws, size_t ws_size,
                              hipStream_t stream) {
  const float* feature = (const float*)d_in[0];
  const int*   label   = (const int*)d_in[1];
  int*   counts = (int*)d_ws;     // 1000 ints
  float* out    = (float*)d_out;

  bincount_kernel<<<1, 1024, 0, stream>>>(label, counts, out);
  rowloss_kernel<<<MAIN_BLOCKS, 1024, 0, stream>>>(feature, label, counts, out);
}

// Round 4
// 94.421 us; speedup vs baseline: 1.0531x; 1.0531x over previous
//
#include <hip/hip_runtime.h>
#include <math.h>

#define N_ROWS 16384
#define N_COLS 1000
#define WAVES_PER_BLOCK 4
#define MAIN_BLOCKS (N_ROWS / WAVES_PER_BLOCK)  // 4096

// ws layout: S[1024] float (per-class sum of beta*logp), cnt[1024] int.
// Zeroed by hipMemsetAsync before the main kernel.

// ---------------------------------------------------------------------------
// Main kernel: one wave per row. Row of 1000 f32 staged in 16 regs/lane via
// coalesced float4 loads; butterfly max; exp2-based sum; per-class scattered
// atomics (one from lane 0, one from lane 1). No LDS, no __syncthreads.
// Decomposition: loss = -(1/N) * sum_c alpha(n_c) * S_c,
// S_c = sum_{i: label_i = c} beta_i * logp_i  — counts not needed per-row.
// ---------------------------------------------------------------------------
__global__ __launch_bounds__(256) void rowloss_kernel(
    const float* __restrict__ feature, const int* __restrict__ label,
    float* __restrict__ S, int* __restrict__ cnt) {
  const int wave = threadIdx.x >> 6;
  const int lane = threadIdx.x & 63;
  const int row  = blockIdx.x * WAVES_PER_BLOCK + wave;
  const float* rowp = feature + (size_t)row * N_COLS;

  // Early wave-uniform loads; latency hides under the float4 stream.
  const int   lab = label[row];
  const float xl  = rowp[lab];

  // Coalesced staging: step k covers elements [k*256,(k+1)*256); lane l takes
  // the float4 at k*256 + l*4. Row base 4000 B = 16B-aligned; 1000%4==0 so
  // any in-bounds float4 is fully in-bounds (last is 996..999 at lane 57).
  float4 v[4];
#pragma unroll
  for (int k = 0; k < 4; ++k) {
    const int e = k * 256 + lane * 4;
    v[k] = (e < N_COLS) ? *reinterpret_cast<const float4*>(rowp + e)
                        : make_float4(-INFINITY, -INFINITY, -INFINITY, -INFINITY);
  }

  // Row max.
  float m = fmaxf(fmaxf(v[0].x, v[0].y), fmaxf(v[0].z, v[0].w));
#pragma unroll
  for (int k = 1; k < 4; ++k)
    m = fmaxf(m, fmaxf(fmaxf(v[k].x, v[k].y), fmaxf(v[k].z, v[k].w)));
#pragma unroll
  for (int off = 32; off > 0; off >>= 1) m = fmaxf(m, __shfl_xor(m, off));

  // sum(exp(x-m)) via exp2 (v_exp_f32); -inf pads contribute 0.
  const float LOG2E = 1.4426950408889634f;
  const float mL = m * LOG2E;
  float s = 0.0f;
#pragma unroll
  for (int k = 0; k < 4; ++k) {
    s += exp2f(fmaf(v[k].x, LOG2E, -mL));
    s += exp2f(fmaf(v[k].y, LOG2E, -mL));
    s += exp2f(fmaf(v[k].z, LOG2E, -mL));
    s += exp2f(fmaf(v[k].w, LOG2E, -mL));
  }
#pragma unroll
  for (int off = 32; off > 0; off >>= 1) s += __shfl_xor(s, off);

  const float logp = xl - m - logf(s);
  const float p    = expf(logp);
  const float beta = (1.0f - p) * (1.0f - p);

  // Two scattered atomics per wave, issued from different lanes so they
  // dual-issue. ~16 rows/class -> negligible contention.
  if (lane == 0) atomicAdd(&S[lab], beta * logp);
  if (lane == 1) atomicAdd(&cnt[lab], 1);
}

// ---------------------------------------------------------------------------
// Finalize: 1 block. out = -(1/N) * sum_c alpha(n_c/N) * S_c, skipping empty
// classes (avoids 0 * inf from alpha at r=0).
// ---------------------------------------------------------------------------
__global__ __launch_bounds__(1024) void finalize_kernel(
    const float* __restrict__ S, const int* __restrict__ cnt,
    float* __restrict__ out) {
  __shared__ float lds[1024];
  float t = 0.0f;
  const int c = threadIdx.x;
  if (c < N_COLS) {
    const int n = cnt[c];
    if (n > 0) {
      const float r = (float)n * (1.0f / (float)N_ROWS);
      const float alpha = expf(r - 1.0f) / r;
      t = alpha * S[c];
    }
  }
  lds[threadIdx.x] = t;
  __syncthreads();
  for (int off = 512; off > 0; off >>= 1) {
    if (threadIdx.x < off) lds[threadIdx.x] += lds[threadIdx.x + off];
    __syncthreads();
  }
  if (threadIdx.x == 0) out[0] = -lds[0] * (1.0f / (float)N_ROWS);
}

// ---------------------------------------------------------------------------
extern "C" void kernel_launch(void* const* d_in, const int* in_sizes, int n_in,
                              void* d_out, int out_size, void* d_ws, size_t ws_size,
                              hipStream_t stream) {
  const float* feature = (const float*)d_in[0];
  const int*   label   = (const int*)d_in[1];
  float* S   = (float*)d_ws;           // 1024 floats
  int*   cnt = (int*)d_ws + 1024;      // 1024 ints
  float* out = (float*)d_out;

  hipMemsetAsync(d_ws, 0, 8192, stream);  // zero S + cnt (capturable)
  rowloss_kernel<<<MAIN_BLOCKS, 256, 0, stream>>>(feature, label, S, cnt);
  finalize_kernel<<<1, 1024, 0, stream>>>(S, cnt, out);
}